// Round 2
// baseline (226.968 us; speedup 1.0000x reference)
//
#include <hip/hip_runtime.h>

// Problem constants (match reference setup_inputs).
constexpr int B   = 4;
constexpr int N   = 20000;
constexpr int E   = 320000;
constexpr int INF = 128;     // input features
constexpr int H   = 4;       // heads
constexpr int F   = 32;      // out features per head
constexpr int HF  = H * F;   // 128

// ---------------------------------------------------------------- utilities
__global__ __launch_bounds__(256) void zero_deg_kernel(int* __restrict__ deg) {
    int i = blockIdx.x * 256 + threadIdx.x;
    if (i < N) deg[i] = 0;
}

// ---------------------------------------------------------------- GEMM: h = x @ W
// x: [B*N][128] row-major, W: [128][128], h written as [n][b][128] (batch-interleaved).
// Tile: 32 rows x 128 cols per block; thread = 4 rows x 4 cols (16 accs).
// W staged in two 64-k phases (32 KB each) + transposed x tile (8 KB) -> 40 KB LDS.
__global__ __launch_bounds__(256) void gemm_kernel(const float* __restrict__ x,
                                                   const float* __restrict__ W,
                                                   float* __restrict__ h) {
    __shared__ float Ws[64 * HF];   // 32 KB
    __shared__ float xs[64][32];    // 8 KB, k-major (transposed)

    const int t     = threadIdx.x;
    const int row0  = blockIdx.x * 32;
    const int c0    = (t & 31) * 4;   // 4 consecutive output cols
    const int rbase = (t >> 5) * 4;   // 4 consecutive rows within tile

    float acc[4][4];
#pragma unroll
    for (int r = 0; r < 4; ++r)
#pragma unroll
        for (int j = 0; j < 4; ++j) acc[r][j] = 0.f;

    for (int ph = 0; ph < 2; ++ph) {
        const int kbase = ph * 64;
        if (ph) __syncthreads();   // protect LDS re-stage

        // stage W rows kbase..kbase+63 (8192 floats = 2048 float4)
        {
            const float4* Wg = (const float4*)(W + (size_t)kbase * HF);
            float4* Wl = (float4*)Ws;
#pragma unroll
            for (int i = 0; i < 8; ++i) Wl[t + i * 256] = Wg[t + i * 256];
        }
        // stage x tile transposed: xs[k][row]
        {
            const int rr = t & 31;
            const int kc = (t >> 5) * 8;
            const float4* xr = (const float4*)(x + (size_t)(row0 + rr) * INF + kbase + kc);
#pragma unroll
            for (int i = 0; i < 2; ++i) {
                float4 q = xr[i];
                xs[kc + i * 4 + 0][rr] = q.x;
                xs[kc + i * 4 + 1][rr] = q.y;
                xs[kc + i * 4 + 2][rr] = q.z;
                xs[kc + i * 4 + 3][rr] = q.w;
            }
        }
        __syncthreads();

#pragma unroll 8
        for (int k = 0; k < 64; ++k) {
            const float4 w4 = *(const float4*)&Ws[k * HF + c0];
            const float4 x4 = *(const float4*)&xs[k][rbase];
            acc[0][0] += x4.x * w4.x; acc[0][1] += x4.x * w4.y; acc[0][2] += x4.x * w4.z; acc[0][3] += x4.x * w4.w;
            acc[1][0] += x4.y * w4.x; acc[1][1] += x4.y * w4.y; acc[1][2] += x4.y * w4.z; acc[1][3] += x4.y * w4.w;
            acc[2][0] += x4.z * w4.x; acc[2][1] += x4.z * w4.y; acc[2][2] += x4.z * w4.z; acc[2][3] += x4.z * w4.w;
            acc[3][0] += x4.w * w4.x; acc[3][1] += x4.w * w4.y; acc[3][2] += x4.w * w4.z; acc[3][3] += x4.w * w4.w;
        }
    }

    // write h in [n][b][HF] layout; each 32-row tile stays within one batch
    // since N % 32 == 0.
#pragma unroll
    for (int r = 0; r < 4; ++r) {
        const int row = row0 + rbase + r;
        const int b   = row / N;
        const int n   = row - b * N;
        float4 v = {acc[r][0], acc[r][1], acc[r][2], acc[r][3]};
        *(float4*)(h + ((size_t)n * B + b) * HF + c0) = v;
    }
}

// ---------------------------------------------------------------- per-node attention scalars
// asrc[idx] = h_row . a[h,:F],  adst[idx] = h_row . a[h,F:],  idx = (n*B+b)*H + hh
__global__ __launch_bounds__(256) void alpha_kernel(const float* __restrict__ h,
                                                    const float* __restrict__ a,
                                                    float* __restrict__ asrc,
                                                    float* __restrict__ adst) {
    int idx = blockIdx.x * 256 + threadIdx.x;
    if (idx >= N * B * H) return;
    const int hh = idx & (H - 1);
    const float4* hr = (const float4*)(h + (size_t)idx * F);
    const float4* a1 = (const float4*)(a + hh * 2 * F);
    const float4* a2 = (const float4*)(a + hh * 2 * F + F);
    float s1 = 0.f, s2 = 0.f;
#pragma unroll
    for (int q = 0; q < 8; ++q) {
        float4 hv = hr[q], u = a1[q], v = a2[q];
        s1 += hv.x * u.x + hv.y * u.y + hv.z * u.z + hv.w * u.w;
        s2 += hv.x * v.x + hv.y * v.y + hv.z * v.z + hv.w * v.w;
    }
    asrc[idx] = s1;
    adst[idx] = s2;
}

// ---------------------------------------------------------------- CSR build
// edge_index arrives as int32 (harness converts all integer inputs to int32):
// ei[0..E) = src row, ei[E..2E) = dst row.
__global__ __launch_bounds__(256) void hist_kernel(const int* __restrict__ dst,
                                                   int* __restrict__ deg) {
    int e = blockIdx.x * 256 + threadIdx.x;
    if (e < E) atomicAdd(&deg[dst[e]], 1);
}

__global__ __launch_bounds__(1024) void scan_kernel(const int* __restrict__ deg,
                                                    int* __restrict__ offsets,
                                                    int* __restrict__ cursor) {
    __shared__ int part[1024];
    const int t  = threadIdx.x;
    const int CH = (N + 1023) / 1024;     // 20
    const int b0 = t * CH;
    const int b1 = min(b0 + CH, N);
    int s = 0;
    for (int i = b0; i < b1; ++i) s += deg[i];
    part[t] = s;
    __syncthreads();
    for (int off = 1; off < 1024; off <<= 1) {
        int v = (t >= off) ? part[t - off] : 0;
        __syncthreads();
        part[t] += v;
        __syncthreads();
    }
    int run = (t == 0) ? 0 : part[t - 1];
    for (int i = b0; i < b1; ++i) {
        offsets[i] = run;
        cursor[i]  = run;
        run += deg[i];
    }
    if (t == 1023) offsets[N] = part[1023];
}

__global__ __launch_bounds__(256) void fill_kernel(const int* __restrict__ ei,
                                                   int* __restrict__ cursor,
                                                   int* __restrict__ csr) {
    int e = blockIdx.x * 256 + threadIdx.x;
    if (e >= E) return;
    const int s = ei[e];          // src row
    const int d = ei[E + e];      // dst row
    const int pos = atomicAdd(&cursor[d], 1);
    csr[pos] = s;
}

// ---------------------------------------------------------------- gather/aggregate
// block = node n; wave b handles batch b; lane owns 2 of 128 (h,f) elements.
// out[b,n,:] = (sum_e exp(lrelu(asrc[s]+adst[n])) * h[s]) / (sum_e exp + 1e-10)
__global__ __launch_bounds__(256) void gather_kernel(const float* __restrict__ h,
                                                     const float* __restrict__ asrc,
                                                     const float* __restrict__ adst,
                                                     const int* __restrict__ offsets,
                                                     const int* __restrict__ csr,
                                                     float* __restrict__ out) {
    const int n  = blockIdx.x;
    const int t  = threadIdx.x;
    const int b  = t >> 6;
    const int l  = t & 63;
    const int hh = l >> 4;             // head for this lane's 2 elements

    const float ad = adst[((size_t)n * B + b) * H + hh];
    const int j0 = offsets[n];
    const int j1 = offsets[n + 1];

    float accx = 0.f, accy = 0.f, den = 0.f;
    for (int j = j0; j < j1; ++j) {
        const int s = csr[j];
        float att = asrc[((size_t)s * B + b) * H + hh] + ad;
        att = (att >= 0.f) ? att : 0.2f * att;
        const float ex = __expf(att);
        den += ex;
        const float2 hv = *(const float2*)(h + ((size_t)s * B + b) * HF + 2 * l);
        accx += ex * hv.x;
        accy += ex * hv.y;
    }
    const float inv = 1.0f / (den + 1e-10f);
    float2 o = {accx * inv, accy * inv};
    *(float2*)(out + ((size_t)b * N + n) * HF + 2 * l) = o;
}

// ---------------------------------------------------------------- launch
extern "C" void kernel_launch(void* const* d_in, const int* in_sizes, int n_in,
                              void* d_out, int out_size, void* d_ws, size_t ws_size,
                              hipStream_t stream) {
    const float* x   = (const float*)d_in[0];
    const int*   ei  = (const int*)d_in[1];     // int32! (harness converts int64 -> int32)
    const float* W   = (const float*)d_in[2];
    const float* a   = (const float*)d_in[3];
    float*       out = (float*)d_out;

    // workspace carve (~45.1 MB total)
    char* p = (char*)d_ws;
    float* h    = (float*)p; p += (size_t)B * N * HF * sizeof(float);   // 40,960,000 B
    float* asrc = (float*)p; p += (size_t)N * B * H * sizeof(float);    //  1,280,000 B
    float* adst = (float*)p; p += (size_t)N * B * H * sizeof(float);    //  1,280,000 B
    int* deg     = (int*)p;  p += 80128;
    int* offsets = (int*)p;  p += 80128;
    int* cursor  = (int*)p;  p += 80128;
    int* csr     = (int*)p;  p += (size_t)E * sizeof(int);              //  1,280,000 B

    zero_deg_kernel<<<(N + 255) / 256, 256, 0, stream>>>(deg);
    gemm_kernel<<<(B * N) / 32, 256, 0, stream>>>(x, W, h);
    alpha_kernel<<<(N * B * H + 255) / 256, 256, 0, stream>>>(h, a, asrc, adst);
    hist_kernel<<<(E + 255) / 256, 256, 0, stream>>>(ei + E, deg);
    scan_kernel<<<1, 1024, 0, stream>>>(deg, offsets, cursor);
    fill_kernel<<<(E + 255) / 256, 256, 0, stream>>>(ei, cursor, csr);
    gather_kernel<<<N, 256, 0, stream>>>(h, asrc, adst, offsets, csr, out);
}

// Round 3
// 187.393 us; speedup vs baseline: 1.2112x; 1.2112x over previous
//
#include <hip/hip_runtime.h>
#include <hip/hip_bf16.h>

// Problem constants (match reference setup_inputs).
constexpr int B   = 4;
constexpr int N   = 20000;
constexpr int E   = 320000;
constexpr int INF = 128;     // input features
constexpr int H   = 4;       // heads
constexpr int F   = 32;      // out features per head
constexpr int HF  = H * F;   // 128

__device__ __forceinline__ float bflo(unsigned v) { return __uint_as_float(v << 16); }
__device__ __forceinline__ float bfhi(unsigned v) { return __uint_as_float(v & 0xffff0000u); }
__device__ __forceinline__ unsigned pack_bf2(float a, float b) {
    __hip_bfloat162 t = __float22bfloat162_rn(float2{a, b});
    return *(unsigned*)&t;
}

// ---------------------------------------------------------------- utilities
__global__ __launch_bounds__(256) void zero_deg_kernel(int* __restrict__ deg) {
    int i = blockIdx.x * 256 + threadIdx.x;
    if (i < N) deg[i] = 0;
}

// ---------------------------------------------------------------- GEMM: h = x @ W  (bf16 output)
// x: [B*N][128] row-major, W: [128][128], hb written bf16 as [n][b][128].
// Tile: 32 rows x 128 cols per block; thread = 4 rows x 4 cols (16 accs).
__global__ __launch_bounds__(256) void gemm_kernel(const float* __restrict__ x,
                                                   const float* __restrict__ W,
                                                   __hip_bfloat16* __restrict__ hb) {
    __shared__ float Ws[64 * HF];   // 32 KB
    __shared__ float xs[64][32];    // 8 KB, k-major (transposed)

    const int t     = threadIdx.x;
    const int row0  = blockIdx.x * 32;
    const int c0    = (t & 31) * 4;   // 4 consecutive output cols
    const int rbase = (t >> 5) * 4;   // 4 consecutive rows within tile

    float acc[4][4];
#pragma unroll
    for (int r = 0; r < 4; ++r)
#pragma unroll
        for (int j = 0; j < 4; ++j) acc[r][j] = 0.f;

    for (int ph = 0; ph < 2; ++ph) {
        const int kbase = ph * 64;
        if (ph) __syncthreads();

        {
            const float4* Wg = (const float4*)(W + (size_t)kbase * HF);
            float4* Wl = (float4*)Ws;
#pragma unroll
            for (int i = 0; i < 8; ++i) Wl[t + i * 256] = Wg[t + i * 256];
        }
        {
            const int rr = t & 31;
            const int kc = (t >> 5) * 8;
            const float4* xr = (const float4*)(x + (size_t)(row0 + rr) * INF + kbase + kc);
#pragma unroll
            for (int i = 0; i < 2; ++i) {
                float4 q = xr[i];
                xs[kc + i * 4 + 0][rr] = q.x;
                xs[kc + i * 4 + 1][rr] = q.y;
                xs[kc + i * 4 + 2][rr] = q.z;
                xs[kc + i * 4 + 3][rr] = q.w;
            }
        }
        __syncthreads();

#pragma unroll 8
        for (int k = 0; k < 64; ++k) {
            const float4 w4 = *(const float4*)&Ws[k * HF + c0];
            const float4 x4 = *(const float4*)&xs[k][rbase];
            acc[0][0] += x4.x * w4.x; acc[0][1] += x4.x * w4.y; acc[0][2] += x4.x * w4.z; acc[0][3] += x4.x * w4.w;
            acc[1][0] += x4.y * w4.x; acc[1][1] += x4.y * w4.y; acc[1][2] += x4.y * w4.z; acc[1][3] += x4.y * w4.w;
            acc[2][0] += x4.z * w4.x; acc[2][1] += x4.z * w4.y; acc[2][2] += x4.z * w4.z; acc[2][3] += x4.z * w4.w;
            acc[3][0] += x4.w * w4.x; acc[3][1] += x4.w * w4.y; acc[3][2] += x4.w * w4.z; acc[3][3] += x4.w * w4.w;
        }
    }

    // write hb (bf16) in [n][b][HF] layout; tiles never cross batch (N % 32 == 0)
#pragma unroll
    for (int r = 0; r < 4; ++r) {
        const int row = row0 + rbase + r;
        const int b   = row / N;
        const int n   = row - b * N;
        uint2 w;
        w.x = pack_bf2(acc[r][0], acc[r][1]);
        w.y = pack_bf2(acc[r][2], acc[r][3]);
        *(uint2*)(hb + ((size_t)n * B + b) * HF + c0) = w;   // 8B aligned (c0 % 4 == 0)
    }
}

// ---------------------------------------------------------------- per-node attention scalars
// asrc[idx] = h_row . a[h,:F],  adst[idx] = h_row . a[h,F:],  idx = (n*B+b)*H + hh
__global__ __launch_bounds__(256) void alpha_kernel(const __hip_bfloat16* __restrict__ hb,
                                                    const float* __restrict__ a,
                                                    float* __restrict__ asrc,
                                                    float* __restrict__ adst) {
    int idx = blockIdx.x * 256 + threadIdx.x;
    if (idx >= N * B * H) return;
    const int hh = idx & (H - 1);
    const uint4*  hr = (const uint4*)(hb + (size_t)idx * F);   // 8 bf16 per uint4
    const float4* a1 = (const float4*)(a + hh * 2 * F);
    const float4* a2 = (const float4*)(a + hh * 2 * F + F);
    float s1 = 0.f, s2 = 0.f;
#pragma unroll
    for (int q = 0; q < 4; ++q) {
        uint4 v = hr[q];
        float h0 = bflo(v.x), h1 = bfhi(v.x), h2 = bflo(v.y), h3 = bfhi(v.y);
        float h4 = bflo(v.z), h5 = bfhi(v.z), h6 = bflo(v.w), h7 = bfhi(v.w);
        float4 u0 = a1[2 * q], u1 = a1[2 * q + 1];
        float4 w0 = a2[2 * q], w1 = a2[2 * q + 1];
        s1 += h0 * u0.x + h1 * u0.y + h2 * u0.z + h3 * u0.w
            + h4 * u1.x + h5 * u1.y + h6 * u1.z + h7 * u1.w;
        s2 += h0 * w0.x + h1 * w0.y + h2 * w0.z + h3 * w0.w
            + h4 * w1.x + h5 * w1.y + h6 * w1.z + h7 * w1.w;
    }
    asrc[idx] = s1;
    adst[idx] = s2;
}

// ---------------------------------------------------------------- CSR build (edge_index is int32)
__global__ __launch_bounds__(256) void hist_kernel(const int* __restrict__ dst,
                                                   int* __restrict__ deg) {
    int e = blockIdx.x * 256 + threadIdx.x;
    if (e < E) atomicAdd(&deg[dst[e]], 1);
}

__global__ __launch_bounds__(1024) void scan_kernel(const int* __restrict__ deg,
                                                    int* __restrict__ offsets,
                                                    int* __restrict__ cursor) {
    __shared__ int part[1024];
    const int t  = threadIdx.x;
    const int CH = (N + 1023) / 1024;     // 20
    const int b0 = t * CH;
    const int b1 = min(b0 + CH, N);
    int s = 0;
    for (int i = b0; i < b1; ++i) s += deg[i];
    part[t] = s;
    __syncthreads();
    for (int off = 1; off < 1024; off <<= 1) {
        int v = (t >= off) ? part[t - off] : 0;
        __syncthreads();
        part[t] += v;
        __syncthreads();
    }
    int run = (t == 0) ? 0 : part[t - 1];
    for (int i = b0; i < b1; ++i) {
        offsets[i] = run;
        cursor[i]  = run;
        run += deg[i];
    }
    if (t == 1023) offsets[N] = part[1023];
}

__global__ __launch_bounds__(256) void fill_kernel(const int* __restrict__ ei,
                                                   int* __restrict__ cursor,
                                                   int* __restrict__ csr) {
    int e = blockIdx.x * 256 + threadIdx.x;
    if (e >= E) return;
    const int s = ei[e];          // src row
    const int d = ei[E + e];      // dst row
    const int pos = atomicAdd(&cursor[d], 1);
    csr[pos] = s;
}

// ---------------------------------------------------------------- gather/aggregate (bf16 h)
// block = node n; wave b handles batch b; lane owns bf16 pair l (elems 2l,2l+1).
__global__ __launch_bounds__(256) void gather_kernel(const __hip_bfloat16* __restrict__ hb,
                                                     const float* __restrict__ asrc,
                                                     const float* __restrict__ adst,
                                                     const int* __restrict__ offsets,
                                                     const int* __restrict__ csr,
                                                     float* __restrict__ out) {
    const int n  = blockIdx.x;
    const int t  = threadIdx.x;
    const int b  = t >> 6;
    const int l  = t & 63;
    const int hh = l >> 4;             // head for this lane's 2 elements

    const unsigned* hu = (const unsigned*)hb;     // pair index = (s*B+b)*64 + l
    const float ad = adst[((size_t)n * B + b) * H + hh];
    const int j0 = offsets[n];
    const int j1 = offsets[n + 1];

    float accx = 0.f, accy = 0.f, den = 0.f;
    int j = j0;
    for (; j + 1 < j1; j += 2) {       // unroll x2: two independent load chains
        const int s0 = csr[j];
        const int s1 = csr[j + 1];
        const float a0 = asrc[((size_t)s0 * B + b) * H + hh];
        const float a1 = asrc[((size_t)s1 * B + b) * H + hh];
        const unsigned v0 = hu[((size_t)s0 * B + b) * 64 + l];
        const unsigned v1 = hu[((size_t)s1 * B + b) * 64 + l];
        float t0 = a0 + ad; t0 = (t0 >= 0.f) ? t0 : 0.2f * t0;
        float t1 = a1 + ad; t1 = (t1 >= 0.f) ? t1 : 0.2f * t1;
        const float e0 = __expf(t0);
        const float e1 = __expf(t1);
        den  += e0 + e1;
        accx += e0 * bflo(v0) + e1 * bflo(v1);
        accy += e0 * bfhi(v0) + e1 * bfhi(v1);
    }
    if (j < j1) {
        const int s0 = csr[j];
        const float a0 = asrc[((size_t)s0 * B + b) * H + hh];
        const unsigned v0 = hu[((size_t)s0 * B + b) * 64 + l];
        float t0 = a0 + ad; t0 = (t0 >= 0.f) ? t0 : 0.2f * t0;
        const float e0 = __expf(t0);
        den  += e0;
        accx += e0 * bflo(v0);
        accy += e0 * bfhi(v0);
    }
    const float inv = 1.0f / (den + 1e-10f);
    float2 o = {accx * inv, accy * inv};
    *(float2*)(out + ((size_t)b * N + n) * HF + 2 * l) = o;
}

// ---------------------------------------------------------------- launch
extern "C" void kernel_launch(void* const* d_in, const int* in_sizes, int n_in,
                              void* d_out, int out_size, void* d_ws, size_t ws_size,
                              hipStream_t stream) {
    const float* x   = (const float*)d_in[0];
    const int*   ei  = (const int*)d_in[1];     // int32 (harness converts int64 -> int32)
    const float* W   = (const float*)d_in[2];
    const float* a   = (const float*)d_in[3];
    float*       out = (float*)d_out;

    // workspace carve (~25 MB total)
    char* p = (char*)d_ws;
    __hip_bfloat16* hb = (__hip_bfloat16*)p; p += (size_t)B * N * HF * sizeof(__hip_bfloat16); // 20,480,000 B
    float* asrc = (float*)p; p += (size_t)N * B * H * sizeof(float);    // 1,280,000 B
    float* adst = (float*)p; p += (size_t)N * B * H * sizeof(float);    // 1,280,000 B
    int* deg     = (int*)p;  p += 80128;
    int* offsets = (int*)p;  p += 80128;
    int* cursor  = (int*)p;  p += 80128;
    int* csr     = (int*)p;  p += (size_t)E * sizeof(int);              // 1,280,000 B

    zero_deg_kernel<<<(N + 255) / 256, 256, 0, stream>>>(deg);
    gemm_kernel<<<(B * N) / 32, 256, 0, stream>>>(x, W, hb);
    alpha_kernel<<<(N * B * H + 255) / 256, 256, 0, stream>>>(hb, a, asrc, adst);
    hist_kernel<<<(E + 255) / 256, 256, 0, stream>>>(ei + E, deg);
    scan_kernel<<<1, 1024, 0, stream>>>(deg, offsets, cursor);
    fill_kernel<<<(E + 255) / 256, 256, 0, stream>>>(ei, cursor, csr);
    gather_kernel<<<N, 256, 0, stream>>>(hb, asrc, adst, offsets, csr, out);
}

// Round 5
// 143.459 us; speedup vs baseline: 1.5821x; 1.3062x over previous
//
#include <hip/hip_runtime.h>
#include <hip/hip_bf16.h>

// Problem constants (match reference setup_inputs).
constexpr int B   = 4;
constexpr int N   = 20000;
constexpr int E   = 320000;
constexpr int INF = 128;     // input features
constexpr int H   = 4;       // heads
constexpr int F   = 32;      // out features per head
constexpr int HF  = H * F;   // 128

__device__ __forceinline__ float bflo(unsigned v) { return __uint_as_float(v << 16); }
__device__ __forceinline__ float bfhi(unsigned v) { return __uint_as_float(v & 0xffff0000u); }
__device__ __forceinline__ unsigned pack_bf2(float a, float b) {
    __hip_bfloat162 t = __float22bfloat162_rn(float2{a, b});
    return *(unsigned*)&t;
}

// ---------------------------------------------------------------- utilities
__global__ __launch_bounds__(256) void zero_deg_kernel(int* __restrict__ deg) {
    int i = blockIdx.x * 256 + threadIdx.x;
    if (i < N) deg[i] = 0;
}

// ---------------------------------------------------------------- GEMM + alpha fused
// h = x @ W (bf16 out, [n][b][128] layout) and asrc/adst per (n,b,head).
// Tile: 64 rows x 128 cols, 256 threads, thread = 4 rows x 8 cols (32 accs).
// Two 64-k phases: Ws[64][128] (32 KB) + xs[64][64] transposed (16 KB) = 48 KB LDS.
__global__ __launch_bounds__(256) void gemm_alpha_kernel(const float* __restrict__ x,
                                                         const float* __restrict__ W,
                                                         const float* __restrict__ a,
                                                         __hip_bfloat16* __restrict__ hb,
                                                         float* __restrict__ asrc,
                                                         float* __restrict__ adst) {
    __shared__ float Ws[64 * HF];   // 32 KB
    __shared__ float xs[64][64];    // 16 KB, k-major (transposed)

    const int t     = threadIdx.x;
    const int row0  = blockIdx.x * 64;
    const int c0    = (t & 15) * 8;   // 8 consecutive output cols (never crosses a head)
    const int rbase = (t >> 4) * 4;   // 4 consecutive rows within tile

    float acc[4][8];
#pragma unroll
    for (int r = 0; r < 4; ++r)
#pragma unroll
        for (int j = 0; j < 8; ++j) acc[r][j] = 0.f;

    for (int ph = 0; ph < 2; ++ph) {
        const int kbase = ph * 64;
        if (ph) __syncthreads();

        // stage W rows kbase..kbase+63 (8192 floats = 2048 float4)
        {
            const float4* Wg = (const float4*)(W + (size_t)kbase * HF);
            float4* Wl = (float4*)Ws;
#pragma unroll
            for (int i = 0; i < 8; ++i) Wl[t + i * 256] = Wg[t + i * 256];
        }
        // stage x tile transposed: xs[k][row]; 64 rows x 64 k
        {
            const int rr = t & 63;
            const int kg = (t >> 6) * 16;
            const float4* xr = (const float4*)(x + (size_t)(row0 + rr) * INF + kbase + kg);
#pragma unroll
            for (int i = 0; i < 4; ++i) {
                float4 q = xr[i];
                xs[kg + i * 4 + 0][rr] = q.x;
                xs[kg + i * 4 + 1][rr] = q.y;
                xs[kg + i * 4 + 2][rr] = q.z;
                xs[kg + i * 4 + 3][rr] = q.w;
            }
        }
        __syncthreads();

#pragma unroll 4
        for (int k = 0; k < 64; ++k) {
            const float4 w0 = *(const float4*)&Ws[k * HF + c0];
            const float4 w1 = *(const float4*)&Ws[k * HF + c0 + 4];
            const float4 x4 = *(const float4*)&xs[k][rbase];
            const float xr0 = x4.x, xr1 = x4.y, xr2 = x4.z, xr3 = x4.w;
            acc[0][0] += xr0 * w0.x; acc[0][1] += xr0 * w0.y; acc[0][2] += xr0 * w0.z; acc[0][3] += xr0 * w0.w;
            acc[0][4] += xr0 * w1.x; acc[0][5] += xr0 * w1.y; acc[0][6] += xr0 * w1.z; acc[0][7] += xr0 * w1.w;
            acc[1][0] += xr1 * w0.x; acc[1][1] += xr1 * w0.y; acc[1][2] += xr1 * w0.z; acc[1][3] += xr1 * w0.w;
            acc[1][4] += xr1 * w1.x; acc[1][5] += xr1 * w1.y; acc[1][6] += xr1 * w1.z; acc[1][7] += xr1 * w1.w;
            acc[2][0] += xr2 * w0.x; acc[2][1] += xr2 * w0.y; acc[2][2] += xr2 * w0.z; acc[2][3] += xr2 * w0.w;
            acc[2][4] += xr2 * w1.x; acc[2][5] += xr2 * w1.y; acc[2][6] += xr2 * w1.z; acc[2][7] += xr2 * w1.w;
            acc[3][0] += xr3 * w0.x; acc[3][1] += xr3 * w0.y; acc[3][2] += xr3 * w0.z; acc[3][3] += xr3 * w0.w;
            acc[3][4] += xr3 * w1.x; acc[3][5] += xr3 * w1.y; acc[3][6] += xr3 * w1.z; acc[3][7] += xr3 * w1.w;
        }
    }

    // attention vectors for this thread's 8 cols (head = c0/32)
    const int head = c0 >> 5;
    const int coff = c0 & 31;
    const float4 a1q0 = *(const float4*)(a + head * 2 * F + coff);
    const float4 a1q1 = *(const float4*)(a + head * 2 * F + coff + 4);
    const float4 a2q0 = *(const float4*)(a + head * 2 * F + F + coff);
    const float4 a2q1 = *(const float4*)(a + head * 2 * F + F + coff + 4);

#pragma unroll
    for (int r = 0; r < 4; ++r) {
        const int row = row0 + rbase + r;
        const int b   = row / N;
        const int n   = row - b * N;

        // bf16 h write: 8 cols -> uint4 (16B), 16B-aligned since c0 % 8 == 0
        uint4 w;
        w.x = pack_bf2(acc[r][0], acc[r][1]);
        w.y = pack_bf2(acc[r][2], acc[r][3]);
        w.z = pack_bf2(acc[r][4], acc[r][5]);
        w.w = pack_bf2(acc[r][6], acc[r][7]);
        *(uint4*)(hb + ((size_t)n * B + b) * HF + c0) = w;

        // partial dots for attention scalars
        float s1 = acc[r][0] * a1q0.x + acc[r][1] * a1q0.y + acc[r][2] * a1q0.z + acc[r][3] * a1q0.w
                 + acc[r][4] * a1q1.x + acc[r][5] * a1q1.y + acc[r][6] * a1q1.z + acc[r][7] * a1q1.w;
        float s2 = acc[r][0] * a2q0.x + acc[r][1] * a2q0.y + acc[r][2] * a2q0.z + acc[r][3] * a2q0.w
                 + acc[r][4] * a2q1.x + acc[r][5] * a2q1.y + acc[r][6] * a2q1.z + acc[r][7] * a2q1.w;
        // reduce across the 4 lanes sharing (row-group, head): lanes t^1, t^2
        s1 += __shfl_xor(s1, 1); s1 += __shfl_xor(s1, 2);
        s2 += __shfl_xor(s2, 1); s2 += __shfl_xor(s2, 2);
        if ((t & 3) == 0) {
            const size_t ai = ((size_t)n * B + b) * H + head;
            asrc[ai] = s1;
            adst[ai] = s2;
        }
    }
}

// ---------------------------------------------------------------- CSR build (edge_index is int32)
__global__ __launch_bounds__(256) void hist_kernel(const int* __restrict__ dst,
                                                   int* __restrict__ deg) {
    int e = blockIdx.x * 256 + threadIdx.x;
    if (e < E) atomicAdd(&deg[dst[e]], 1);
}

// single-block scan: exactly 1000 active threads x 20 elements (N = 20000)
__global__ __launch_bounds__(1024) void scan_kernel(const int* __restrict__ deg,
                                                    int* __restrict__ offsets,
                                                    int* __restrict__ cursor) {
    __shared__ int part[1024];
    const int t = threadIdx.x;
    const bool active = (t * 20) < N;     // t < 1000

    int v[20];
    int s = 0;
    if (active) {
        const int4* dp = (const int4*)(deg + t * 20);
#pragma unroll
        for (int i = 0; i < 5; ++i) {
            int4 q = dp[i];
            v[i * 4 + 0] = q.x; v[i * 4 + 1] = q.y; v[i * 4 + 2] = q.z; v[i * 4 + 3] = q.w;
            s += q.x + q.y + q.z + q.w;
        }
    }
    part[t] = s;
    __syncthreads();
    for (int off = 1; off < 1024; off <<= 1) {
        int u = (t >= off) ? part[t - off] : 0;
        __syncthreads();
        part[t] += u;
        __syncthreads();
    }
    if (active) {
        int run = (t == 0) ? 0 : part[t - 1];
        int o[20];
#pragma unroll
        for (int i = 0; i < 20; ++i) { o[i] = run; run += v[i]; }
        int4* op = (int4*)(offsets + t * 20);
        int4* cp = (int4*)(cursor + t * 20);
#pragma unroll
        for (int i = 0; i < 5; ++i) {
            int4 q = {o[i * 4 + 0], o[i * 4 + 1], o[i * 4 + 2], o[i * 4 + 3]};
            op[i] = q;
            cp[i] = q;
        }
        if (t * 20 + 20 >= N) offsets[N] = run;   // t == 999
    }
}

__global__ __launch_bounds__(256) void fill_kernel(const int* __restrict__ ei,
                                                   int* __restrict__ cursor,
                                                   int* __restrict__ csr) {
    int e = blockIdx.x * 256 + threadIdx.x;
    if (e >= E) return;
    const int s = ei[e];          // src row
    const int d = ei[E + e];      // dst row
    const int pos = atomicAdd(&cursor[d], 1);
    csr[pos] = s;
}

// ---------------------------------------------------------------- gather/aggregate (bf16 h)
// block = node n, 128 threads; thread t: batch b = t>>5, feature quad q = t&31
// (features 4q..4q+3, head q>>3). Per edge: one uint2 (4 bf16) load per lane.
// Unroll x4 for 4 independent load chains.
// h quad index for (node s, batch b, quad q) = (s*B + b)*32 + q   [B = 4]
__global__ __launch_bounds__(128) void gather_kernel(const __hip_bfloat16* __restrict__ hb,
                                                     const float* __restrict__ asrc,
                                                     const float* __restrict__ adst,
                                                     const int* __restrict__ offsets,
                                                     const int* __restrict__ csr,
                                                     float* __restrict__ out) {
    const int n  = blockIdx.x;
    const int t  = threadIdx.x;
    const int b  = t >> 5;
    const int q  = t & 31;
    const int hh = q >> 3;

    const uint2* hu = (const uint2*)hb;
    const int bq = b * 32 + q;                    // per-node quad offset
    const int aoff = b * H + hh;                  // asrc idx = s*16 + aoff
    const float ad = adst[(size_t)n * 16 + aoff];
    const int j0 = offsets[n];
    const int j1 = offsets[n + 1];

    float ax = 0.f, ay = 0.f, az = 0.f, aw = 0.f, den = 0.f;
    int j = j0;
    for (; j + 3 < j1; j += 4) {
        const int s0 = csr[j], s1 = csr[j + 1], s2 = csr[j + 2], s3 = csr[j + 3];
        const float l0 = asrc[(size_t)s0 * 16 + aoff];
        const float l1 = asrc[(size_t)s1 * 16 + aoff];
        const float l2 = asrc[(size_t)s2 * 16 + aoff];
        const float l3 = asrc[(size_t)s3 * 16 + aoff];
        const uint2 v0 = hu[(size_t)s0 * 128 + bq];
        const uint2 v1 = hu[(size_t)s1 * 128 + bq];
        const uint2 v2 = hu[(size_t)s2 * 128 + bq];
        const uint2 v3 = hu[(size_t)s3 * 128 + bq];
        float t0 = l0 + ad; t0 = (t0 >= 0.f) ? t0 : 0.2f * t0;
        float t1 = l1 + ad; t1 = (t1 >= 0.f) ? t1 : 0.2f * t1;
        float t2 = l2 + ad; t2 = (t2 >= 0.f) ? t2 : 0.2f * t2;
        float t3 = l3 + ad; t3 = (t3 >= 0.f) ? t3 : 0.2f * t3;
        const float e0 = __expf(t0), e1 = __expf(t1), e2 = __expf(t2), e3 = __expf(t3);
        den += e0 + e1 + e2 + e3;
        ax += e0 * bflo(v0.x) + e1 * bflo(v1.x) + e2 * bflo(v2.x) + e3 * bflo(v3.x);
        ay += e0 * bfhi(v0.x) + e1 * bfhi(v1.x) + e2 * bfhi(v2.x) + e3 * bfhi(v3.x);
        az += e0 * bflo(v0.y) + e1 * bflo(v1.y) + e2 * bflo(v2.y) + e3 * bflo(v3.y);
        aw += e0 * bfhi(v0.y) + e1 * bfhi(v1.y) + e2 * bfhi(v2.y) + e3 * bfhi(v3.y);
    }
    for (; j < j1; ++j) {
        const int s0 = csr[j];
        const float l0 = asrc[(size_t)s0 * 16 + aoff];
        const uint2 v0 = hu[(size_t)s0 * 128 + bq];
        float t0 = l0 + ad; t0 = (t0 >= 0.f) ? t0 : 0.2f * t0;
        const float e0 = __expf(t0);
        den += e0;
        ax += e0 * bflo(v0.x);
        ay += e0 * bfhi(v0.x);
        az += e0 * bflo(v0.y);
        aw += e0 * bfhi(v0.y);
    }
    const float inv = 1.0f / (den + 1e-10f);
    float4 o = {ax * inv, ay * inv, az * inv, aw * inv};
    *(float4*)(out + ((size_t)b * N + n) * HF + q * 4) = o;
}

// ---------------------------------------------------------------- launch
extern "C" void kernel_launch(void* const* d_in, const int* in_sizes, int n_in,
                              void* d_out, int out_size, void* d_ws, size_t ws_size,
                              hipStream_t stream) {
    const float* x   = (const float*)d_in[0];
    const int*   ei  = (const int*)d_in[1];     // int32 (harness converts int64 -> int32)
    const float* W   = (const float*)d_in[2];
    const float* a   = (const float*)d_in[3];
    float*       out = (float*)d_out;

    // workspace carve (~25 MB total)
    char* p = (char*)d_ws;
    __hip_bfloat16* hb = (__hip_bfloat16*)p; p += (size_t)B * N * HF * sizeof(__hip_bfloat16); // 20,480,000 B
    float* asrc = (float*)p; p += (size_t)N * B * H * sizeof(float);    // 1,280,000 B
    float* adst = (float*)p; p += (size_t)N * B * H * sizeof(float);    // 1,280,000 B
    int* deg     = (int*)p;  p += 80128;
    int* offsets = (int*)p;  p += 80128;
    int* cursor  = (int*)p;  p += 80128;
    int* csr     = (int*)p;  p += (size_t)E * sizeof(int);              // 1,280,000 B

    zero_deg_kernel<<<(N + 255) / 256, 256, 0, stream>>>(deg);
    gemm_alpha_kernel<<<(B * N) / 64, 256, 0, stream>>>(x, W, a, hb, asrc, adst);
    hist_kernel<<<(E + 255) / 256, 256, 0, stream>>>(ei + E, deg);
    scan_kernel<<<1, 1024, 0, stream>>>(deg, offsets, cursor);
    fill_kernel<<<(E + 255) / 256, 256, 0, stream>>>(ei, cursor, csr);
    gather_kernel<<<N, 128, 0, stream>>>(hb, asrc, adst, offsets, csr, out);
}

// Round 6
// 121.241 us; speedup vs baseline: 1.8720x; 1.1833x over previous
//
#include <hip/hip_runtime.h>
#include <hip/hip_bf16.h>

// Problem constants (match reference setup_inputs).
constexpr int B   = 4;
constexpr int N   = 20000;
constexpr int E   = 320000;
constexpr int INF = 128;     // input features
constexpr int H   = 4;       // heads
constexpr int F   = 32;      // out features per head
constexpr int HF  = H * F;   // 128

typedef short bf16x8 __attribute__((ext_vector_type(8)));
typedef float f32x4  __attribute__((ext_vector_type(4)));

__device__ __forceinline__ float bflo(unsigned v) { return __uint_as_float(v << 16); }
__device__ __forceinline__ float bfhi(unsigned v) { return __uint_as_float(v & 0xffff0000u); }
__device__ __forceinline__ unsigned pack_bf2(float a, float b) {
    __hip_bfloat162 t = __float22bfloat162_rn(float2{a, b});
    return *(unsigned*)&t;
}

// ---------------------------------------------------------------- utilities
__global__ __launch_bounds__(256) void zero_deg_kernel(int* __restrict__ deg) {
    int i = blockIdx.x * 256 + threadIdx.x;
    if (i < N) deg[i] = 0;
}

// W[128][128] fp32 -> Wt[col][k] bf16 (one-time, 16384 elements)
__global__ __launch_bounds__(256) void wt_kernel(const float* __restrict__ W,
                                                 __hip_bfloat16* __restrict__ wt) {
    int i = blockIdx.x * 256 + threadIdx.x;   // i = c*128 + k
    int c = i >> 7, k = i & 127;
    wt[i] = __float2bfloat16(W[k * HF + c]);
}

// ---------------------------------------------------------------- MFMA GEMM + alpha fused
// h = x @ W (bf16 out, [n][b][128]) and asrc/adst per (n,b,head).
// Block: 64 rows x 128 cols, 256 threads = 4 waves; wave w owns rows w*16..w*16+15.
// A-frags straight from global x (fp32->bf16 in regs); B from swizzled LDS copy of Wt.
// mfma_f32_16x16x32_bf16: A lane l: row=l&15, k=(l>>4)*8+j ; B lane l: col=l&15, k=(l>>4)*8+j ;
// C/D lane l: col=l&15, row=(l>>4)*4+reg  [m89-verified].
__global__ __launch_bounds__(256) void gemm_mfma_kernel(const float* __restrict__ x,
                                                        const __hip_bfloat16* __restrict__ wt,
                                                        const float* __restrict__ a,
                                                        __hip_bfloat16* __restrict__ hb,
                                                        float* __restrict__ asrc,
                                                        float* __restrict__ adst) {
    __shared__ ushort wlds[128 * 128];   // 32 KB, XOR-swizzled: byte ^= ((col&7)<<4)

    const int t    = threadIdx.x;
    const int row0 = blockIdx.x * 64;

    // stage Wt (2048 uint4), applying swizzle; col = byte>>8
    {
        const uint4* wg = (const uint4*)wt;
#pragma unroll
        for (int i = 0; i < 8; ++i) {
            const int idx  = t + i * 256;
            const uint4 v  = wg[idx];
            const int byte = idx * 16;
            const int swz  = byte ^ (((byte >> 8) & 7) << 4);
            *(uint4*)((char*)wlds + swz) = v;
        }
    }

    const int w    = t >> 6;       // wave 0..3
    const int l    = t & 63;
    const int lrow = l & 15;       // A row within band / C,D col
    const int lgrp = l >> 4;       // k-chunk group

    // A-frags from global x: row = row0 + w*16 + lrow, frag kk covers k = kk*32+lgrp*8 .. +7
    bf16x8 afrag[4];
    {
        const int grow = row0 + w * 16 + lrow;
        const float4* xrow = (const float4*)(x + (size_t)grow * INF);
#pragma unroll
        for (int kk = 0; kk < 4; ++kk) {
            const float4 p0 = xrow[kk * 8 + lgrp * 2];
            const float4 p1 = xrow[kk * 8 + lgrp * 2 + 1];
            union { uint4 u; bf16x8 v; } cv;
            cv.u.x = pack_bf2(p0.x, p0.y);
            cv.u.y = pack_bf2(p0.z, p0.w);
            cv.u.z = pack_bf2(p1.x, p1.y);
            cv.u.w = pack_bf2(p1.z, p1.w);
            afrag[kk] = cv.v;
        }
    }

    __syncthreads();   // Wt staged

    f32x4 acc[8];
#pragma unroll
    for (int ct = 0; ct < 8; ++ct) acc[ct] = f32x4{0.f, 0.f, 0.f, 0.f};

#pragma unroll
    for (int ct = 0; ct < 8; ++ct) {
        const int col = ct * 16 + lrow;
#pragma unroll
        for (int kk = 0; kk < 4; ++kk) {
            const int byte = (col * 128 + kk * 32 + lgrp * 8) * 2;
            const int swz  = byte ^ (((byte >> 8) & 7) << 4);
            const bf16x8 bfrag = *(const bf16x8*)((const char*)wlds + swz);
            acc[ct] = __builtin_amdgcn_mfma_f32_16x16x32_bf16(afrag[kk], bfrag, acc[ct], 0, 0, 0);
        }
    }

    // a-vector values for this lane's 8 cols: head = ct>>1, in-head offset = (ct&1)*16+lrow
    float a1v[8], a2v[8];
#pragma unroll
    for (int ct = 0; ct < 8; ++ct) {
        const int head = ct >> 1;
        const int coff = (ct & 1) * 16 + lrow;
        a1v[ct] = a[head * 2 * F + coff];
        a2v[ct] = a[head * 2 * F + F + coff];
    }

    // per-(head,row) partial dots
    float ph1[4][4], ph2[4][4];   // [head][r]
#pragma unroll
    for (int hd = 0; hd < 4; ++hd)
#pragma unroll
        for (int r = 0; r < 4; ++r) { ph1[hd][r] = 0.f; ph2[hd][r] = 0.f; }
#pragma unroll
    for (int ct = 0; ct < 8; ++ct) {
        const int hd = ct >> 1;
#pragma unroll
        for (int r = 0; r < 4; ++r) {
            ph1[hd][r] += acc[ct][r] * a1v[ct];
            ph2[hd][r] += acc[ct][r] * a2v[ct];
        }
    }
    // butterfly over the 16 lanes (lrow) sharing the same rows
#pragma unroll
    for (int m = 1; m < 16; m <<= 1) {
#pragma unroll
        for (int hd = 0; hd < 4; ++hd)
#pragma unroll
            for (int r = 0; r < 4; ++r) {
                ph1[hd][r] += __shfl_xor(ph1[hd][r], m);
                ph2[hd][r] += __shfl_xor(ph2[hd][r], m);
            }
    }

    // writes
#pragma unroll
    for (int r = 0; r < 4; ++r) {
        const int row = row0 + w * 16 + lgrp * 4 + r;
        const int b   = row / N;
        const int n   = row - b * N;
        const size_t hbase = ((size_t)n * B + b) * HF;
#pragma unroll
        for (int ct = 0; ct < 8; ++ct)
            hb[hbase + ct * 16 + lrow] = __float2bfloat16(acc[ct][r]);
        if (lrow == 0) {
            const size_t ai = ((size_t)n * B + b) * H;
#pragma unroll
            for (int hd = 0; hd < 4; ++hd) {
                asrc[ai + hd] = ph1[hd][r];
                adst[ai + hd] = ph2[hd][r];
            }
        }
    }
}

// ---------------------------------------------------------------- CSR build (edge_index is int32)
__global__ __launch_bounds__(256) void hist_kernel(const int* __restrict__ dst,
                                                   int* __restrict__ deg) {
    int e = blockIdx.x * 256 + threadIdx.x;
    if (e < E) atomicAdd(&deg[dst[e]], 1);
}

// single-block scan: exactly 1000 active threads x 20 elements (N = 20000)
__global__ __launch_bounds__(1024) void scan_kernel(const int* __restrict__ deg,
                                                    int* __restrict__ offsets,
                                                    int* __restrict__ cursor) {
    __shared__ int part[1024];
    const int t = threadIdx.x;
    const bool active = (t * 20) < N;     // t < 1000

    int v[20];
    int s = 0;
    if (active) {
        const int4* dp = (const int4*)(deg + t * 20);
#pragma unroll
        for (int i = 0; i < 5; ++i) {
            int4 q = dp[i];
            v[i * 4 + 0] = q.x; v[i * 4 + 1] = q.y; v[i * 4 + 2] = q.z; v[i * 4 + 3] = q.w;
            s += q.x + q.y + q.z + q.w;
        }
    }
    part[t] = s;
    __syncthreads();
    for (int off = 1; off < 1024; off <<= 1) {
        int u = (t >= off) ? part[t - off] : 0;
        __syncthreads();
        part[t] += u;
        __syncthreads();
    }
    if (active) {
        int run = (t == 0) ? 0 : part[t - 1];
        int o[20];
#pragma unroll
        for (int i = 0; i < 20; ++i) { o[i] = run; run += v[i]; }
        int4* op = (int4*)(offsets + t * 20);
        int4* cp = (int4*)(cursor + t * 20);
#pragma unroll
        for (int i = 0; i < 5; ++i) {
            int4 q = {o[i * 4 + 0], o[i * 4 + 1], o[i * 4 + 2], o[i * 4 + 3]};
            op[i] = q;
            cp[i] = q;
        }
        if (t * 20 + 20 >= N) offsets[N] = run;   // t == 999
    }
}

__global__ __launch_bounds__(256) void fill_kernel(const int* __restrict__ ei,
                                                   int* __restrict__ cursor,
                                                   int* __restrict__ csr) {
    int e = blockIdx.x * 256 + threadIdx.x;
    if (e >= E) return;
    const int s = ei[e];          // src row
    const int d = ei[E + e];      // dst row
    const int pos = atomicAdd(&cursor[d], 1);
    csr[pos] = s;
}

// ---------------------------------------------------------------- gather/aggregate (bf16 h)
// one wave per node; lane l: batch b = l>>4, feature octet fq = l&15 (features 8fq..8fq+7),
// head = fq>>2. Per edge each lane loads one uint4 (16 B). x4 unrolled chains.
__global__ __launch_bounds__(64) void gather_kernel(const __hip_bfloat16* __restrict__ hb,
                                                    const float* __restrict__ asrc,
                                                    const float* __restrict__ adst,
                                                    const int* __restrict__ offsets,
                                                    const int* __restrict__ csr,
                                                    float* __restrict__ out) {
    const int n  = blockIdx.x;
    const int l  = threadIdx.x;
    const int b  = l >> 4;
    const int fq = l & 15;
    const int hh = fq >> 2;

    const uint4* hu = (const uint4*)hb;           // idx = (s*B+b)*16 + fq
    const int bq   = b * 16 + fq;
    const int aoff = b * H + hh;                  // asrc idx = s*16 + aoff
    const float ad = adst[(size_t)n * 16 + aoff];
    const int j0 = offsets[n];
    const int j1 = offsets[n + 1];

    float ac[8];
#pragma unroll
    for (int i = 0; i < 8; ++i) ac[i] = 0.f;
    float den = 0.f;

    int j = j0;
    for (; j + 3 < j1; j += 4) {
        const int s0 = csr[j], s1 = csr[j + 1], s2 = csr[j + 2], s3 = csr[j + 3];
        const float l0 = asrc[(size_t)s0 * 16 + aoff];
        const float l1 = asrc[(size_t)s1 * 16 + aoff];
        const float l2 = asrc[(size_t)s2 * 16 + aoff];
        const float l3 = asrc[(size_t)s3 * 16 + aoff];
        const uint4 v0 = hu[(size_t)s0 * 64 + bq];
        const uint4 v1 = hu[(size_t)s1 * 64 + bq];
        const uint4 v2 = hu[(size_t)s2 * 64 + bq];
        const uint4 v3 = hu[(size_t)s3 * 64 + bq];
        float t0 = l0 + ad; t0 = (t0 >= 0.f) ? t0 : 0.2f * t0;
        float t1 = l1 + ad; t1 = (t1 >= 0.f) ? t1 : 0.2f * t1;
        float t2 = l2 + ad; t2 = (t2 >= 0.f) ? t2 : 0.2f * t2;
        float t3 = l3 + ad; t3 = (t3 >= 0.f) ? t3 : 0.2f * t3;
        const float e0 = __expf(t0), e1 = __expf(t1), e2 = __expf(t2), e3 = __expf(t3);
        den += e0 + e1 + e2 + e3;
        ac[0] += e0 * bflo(v0.x) + e1 * bflo(v1.x) + e2 * bflo(v2.x) + e3 * bflo(v3.x);
        ac[1] += e0 * bfhi(v0.x) + e1 * bfhi(v1.x) + e2 * bfhi(v2.x) + e3 * bfhi(v3.x);
        ac[2] += e0 * bflo(v0.y) + e1 * bflo(v1.y) + e2 * bflo(v2.y) + e3 * bflo(v3.y);
        ac[3] += e0 * bfhi(v0.y) + e1 * bfhi(v1.y) + e2 * bfhi(v2.y) + e3 * bfhi(v3.y);
        ac[4] += e0 * bflo(v0.z) + e1 * bflo(v1.z) + e2 * bflo(v2.z) + e3 * bflo(v3.z);
        ac[5] += e0 * bfhi(v0.z) + e1 * bfhi(v1.z) + e2 * bfhi(v2.z) + e3 * bfhi(v3.z);
        ac[6] += e0 * bflo(v0.w) + e1 * bflo(v1.w) + e2 * bflo(v2.w) + e3 * bflo(v3.w);
        ac[7] += e0 * bfhi(v0.w) + e1 * bfhi(v1.w) + e2 * bfhi(v2.w) + e3 * bfhi(v3.w);
    }
    for (; j < j1; ++j) {
        const int s0 = csr[j];
        const float l0 = asrc[(size_t)s0 * 16 + aoff];
        const uint4 v0 = hu[(size_t)s0 * 64 + bq];
        float t0 = l0 + ad; t0 = (t0 >= 0.f) ? t0 : 0.2f * t0;
        const float e0 = __expf(t0);
        den += e0;
        ac[0] += e0 * bflo(v0.x);
        ac[1] += e0 * bfhi(v0.x);
        ac[2] += e0 * bflo(v0.y);
        ac[3] += e0 * bfhi(v0.y);
        ac[4] += e0 * bflo(v0.z);
        ac[5] += e0 * bfhi(v0.z);
        ac[6] += e0 * bflo(v0.w);
        ac[7] += e0 * bfhi(v0.w);
    }
    const float inv = 1.0f / (den + 1e-10f);
    float4 o0 = {ac[0] * inv, ac[1] * inv, ac[2] * inv, ac[3] * inv};
    float4 o1 = {ac[4] * inv, ac[5] * inv, ac[6] * inv, ac[7] * inv};
    float4* op = (float4*)(out + ((size_t)b * N + n) * HF + fq * 8);
    op[0] = o0;
    op[1] = o1;
}

// ---------------------------------------------------------------- launch
extern "C" void kernel_launch(void* const* d_in, const int* in_sizes, int n_in,
                              void* d_out, int out_size, void* d_ws, size_t ws_size,
                              hipStream_t stream) {
    const float* x   = (const float*)d_in[0];
    const int*   ei  = (const int*)d_in[1];     // int32 (harness converts int64 -> int32)
    const float* W   = (const float*)d_in[2];
    const float* a   = (const float*)d_in[3];
    float*       out = (float*)d_out;

    // workspace carve (~25 MB total)
    char* p = (char*)d_ws;
    __hip_bfloat16* hb = (__hip_bfloat16*)p; p += (size_t)B * N * HF * sizeof(__hip_bfloat16); // 20,480,000 B
    float* asrc = (float*)p; p += (size_t)N * B * H * sizeof(float);    // 1,280,000 B
    float* adst = (float*)p; p += (size_t)N * B * H * sizeof(float);    // 1,280,000 B
    int* deg     = (int*)p;  p += 80128;
    int* offsets = (int*)p;  p += 80128;
    int* cursor  = (int*)p;  p += 80128;
    int* csr     = (int*)p;  p += (size_t)E * sizeof(int);              // 1,280,000 B
    __hip_bfloat16* wt = (__hip_bfloat16*)p; p += (size_t)HF * INF * sizeof(__hip_bfloat16); // 32,768 B

    zero_deg_kernel<<<(N + 255) / 256, 256, 0, stream>>>(deg);
    wt_kernel<<<(HF * INF) / 256, 256, 0, stream>>>(W, wt);
    gemm_mfma_kernel<<<(B * N) / 64, 256, 0, stream>>>(x, wt, a, hb, asrc, adst);
    hist_kernel<<<(E + 255) / 256, 256, 0, stream>>>(ei + E, deg);
    scan_kernel<<<1, 1024, 0, stream>>>(deg, offsets, cursor);
    fill_kernel<<<(E + 255) / 256, 256, 0, stream>>>(ei, cursor, csr);
    gather_kernel<<<N, 64, 0, stream>>>(hb, asrc, adst, offsets, csr, out);
}

// Round 8
// 119.111 us; speedup vs baseline: 1.9055x; 1.0179x over previous
//
#include <hip/hip_runtime.h>
#include <hip/hip_bf16.h>

// Problem constants (match reference setup_inputs).
constexpr int B   = 4;
constexpr int N   = 20000;
constexpr int E   = 320000;
constexpr int INF = 128;     // input features
constexpr int H   = 4;       // heads
constexpr int F   = 32;      // out features per head
constexpr int HF  = H * F;   // 128

typedef short bf16x8 __attribute__((ext_vector_type(8)));
typedef float f32x4  __attribute__((ext_vector_type(4)));

__device__ __forceinline__ float bflo(unsigned v) { return __uint_as_float(v << 16); }
__device__ __forceinline__ float bfhi(unsigned v) { return __uint_as_float(v & 0xffff0000u); }
__device__ __forceinline__ unsigned pack_bf2(float a, float b) {
    __hip_bfloat162 t = __float22bfloat162_rn(float2{a, b});
    return *(unsigned*)&t;
}

// ---------------------------------------------------------------- init: deg=0 + Wt transpose
__global__ __launch_bounds__(256) void init_kernel(const float* __restrict__ W,
                                                   __hip_bfloat16* __restrict__ wt,
                                                   int* __restrict__ deg) {
    int i = blockIdx.x * 256 + threadIdx.x;
    if (i < N) deg[i] = 0;
    if (i < HF * INF) {
        int c = i >> 7, k = i & 127;
        wt[i] = __float2bfloat16(W[k * HF + c]);
    }
}

// ---------------------------------------------------------------- MFMA GEMM + alpha fused
// h = x @ W (bf16 out, [n][b][128]) and asrc/adst per (n,b,head).
// Block: 64 rows x 128 cols, 256 threads = 4 waves; wave w owns rows w*16..w*16+15.
// LDS: wlds 32 KB (Wt bf16, [col][k]) + xbds 16 KB (x bf16, [row][k]) = 48 KB total
// (kept < 64 KB deliberately; the 64 KB variant broke under graph capture in R7).
// Both swizzled with byte ^= (((byte>>8)&7)<<4)  (rows are 256 B in both).
// mfma_f32_16x16x32_bf16: A lane l: row=l&15, k=(l>>4)*8+j ; B lane l: col=l&15, k=(l>>4)*8+j ;
// C/D lane l: col=l&15, row=(l>>4)*4+reg  [m89-verified].
__global__ __launch_bounds__(256) void gemm_mfma_kernel(const float* __restrict__ x,
                                                        const __hip_bfloat16* __restrict__ wt,
                                                        const float* __restrict__ a,
                                                        __hip_bfloat16* __restrict__ hb,
                                                        float* __restrict__ asrc,
                                                        float* __restrict__ adst) {
    __shared__ ushort wlds[128 * 128];   // 32 KB
    __shared__ ushort xbds[64 * 128];    // 16 KB

    const int t    = threadIdx.x;
    const int row0 = blockIdx.x * 64;

    // stage Wt (2048 uint4), swizzled; col = byte>>8
    {
        const uint4* wg = (const uint4*)wt;
#pragma unroll
        for (int i = 0; i < 8; ++i) {
            const int idx  = t + i * 256;
            const uint4 v  = wg[idx];
            const int byte = idx * 16;
            const int swz  = byte ^ (((byte >> 8) & 7) << 4);
            *(uint4*)((char*)wlds + swz) = v;
        }
    }
    // stage x rows row0..row0+63: 2048 coalesced float4 reads -> bf16 uint2 (8 B) writes
    {
        const float4* xg = (const float4*)(x + (size_t)row0 * INF);
#pragma unroll
        for (int i = 0; i < 8; ++i) {
            const int idx  = t + i * 256;       // source float4; dest row = (idx*8)>>8
            const float4 q = xg[idx];
            uint2 v;
            v.x = pack_bf2(q.x, q.y);
            v.y = pack_bf2(q.z, q.w);
            const int byte = idx * 8;
            const int swz  = byte ^ (((byte >> 8) & 7) << 4);   // same XOR for both 8B halves of a 16B unit
            *(uint2*)((char*)xbds + swz) = v;
        }
    }

    const int w    = t >> 6;       // wave 0..3
    const int l    = t & 63;
    const int lrow = l & 15;       // A row within band / C,D col
    const int lgrp = l >> 4;       // k-chunk group

    __syncthreads();   // staging done

    // A-frags from swizzled LDS: row = w*16+lrow, frag kk covers k = kk*32+lgrp*8 .. +7
    bf16x8 afrag[4];
    {
        const int arow = w * 16 + lrow;
        const int rswz = (arow & 7) << 4;
#pragma unroll
        for (int kk = 0; kk < 4; ++kk) {
            const int byte = arow * 256 + kk * 64 + lgrp * 16;
            afrag[kk] = *(const bf16x8*)((const char*)xbds + (byte ^ rswz));
        }
    }

    f32x4 acc[8];
#pragma unroll
    for (int ct = 0; ct < 8; ++ct) acc[ct] = f32x4{0.f, 0.f, 0.f, 0.f};

#pragma unroll
    for (int ct = 0; ct < 8; ++ct) {
        const int col = ct * 16 + lrow;
#pragma unroll
        for (int kk = 0; kk < 4; ++kk) {
            const int byte = col * 256 + kk * 64 + lgrp * 16;
            const int swz  = byte ^ (((byte >> 8) & 7) << 4);
            const bf16x8 bfrag = *(const bf16x8*)((const char*)wlds + swz);
            acc[ct] = __builtin_amdgcn_mfma_f32_16x16x32_bf16(afrag[kk], bfrag, acc[ct], 0, 0, 0);
        }
    }

    // a-vector values for this lane's 8 cols: head = ct>>1, in-head offset = (ct&1)*16+lrow
    float a1v[8], a2v[8];
#pragma unroll
    for (int ct = 0; ct < 8; ++ct) {
        const int head = ct >> 1;
        const int coff = (ct & 1) * 16 + lrow;
        a1v[ct] = a[head * 2 * F + coff];
        a2v[ct] = a[head * 2 * F + F + coff];
    }

    // per-(head,row) partial dots
    float ph1[4][4], ph2[4][4];   // [head][r]
#pragma unroll
    for (int hd = 0; hd < 4; ++hd)
#pragma unroll
        for (int r = 0; r < 4; ++r) { ph1[hd][r] = 0.f; ph2[hd][r] = 0.f; }
#pragma unroll
    for (int ct = 0; ct < 8; ++ct) {
        const int hd = ct >> 1;
#pragma unroll
        for (int r = 0; r < 4; ++r) {
            ph1[hd][r] += acc[ct][r] * a1v[ct];
            ph2[hd][r] += acc[ct][r] * a2v[ct];
        }
    }
    // butterfly over the 16 lanes (lrow) sharing the same rows
#pragma unroll
    for (int m = 1; m < 16; m <<= 1) {
#pragma unroll
        for (int hd = 0; hd < 4; ++hd)
#pragma unroll
            for (int r = 0; r < 4; ++r) {
                ph1[hd][r] += __shfl_xor(ph1[hd][r], m);
                ph2[hd][r] += __shfl_xor(ph2[hd][r], m);
            }
    }

    // writes
#pragma unroll
    for (int r = 0; r < 4; ++r) {
        const int row = row0 + w * 16 + lgrp * 4 + r;
        const int b   = row / N;
        const int n   = row - b * N;
        const size_t hbase = ((size_t)n * B + b) * HF;
#pragma unroll
        for (int ct = 0; ct < 8; ++ct)
            hb[hbase + ct * 16 + lrow] = __float2bfloat16(acc[ct][r]);
        if (lrow == 0) {
            const size_t ai = ((size_t)n * B + b) * H;
#pragma unroll
            for (int hd = 0; hd < 4; ++hd) {
                asrc[ai + hd] = ph1[hd][r];
                adst[ai + hd] = ph2[hd][r];
            }
        }
    }
}

// ---------------------------------------------------------------- CSR build (edge_index is int32)
__global__ __launch_bounds__(256) void hist_kernel(const int* __restrict__ dst,
                                                   int* __restrict__ deg) {
    int e = blockIdx.x * 256 + threadIdx.x;
    if (e < E) atomicAdd(&deg[dst[e]], 1);
}

// single-block scan: exactly 1000 active threads x 20 elements (N = 20000)
__global__ __launch_bounds__(1024) void scan_kernel(const int* __restrict__ deg,
                                                    int* __restrict__ offsets,
                                                    int* __restrict__ cursor) {
    __shared__ int part[1024];
    const int t = threadIdx.x;
    const bool active = (t * 20) < N;     // t < 1000

    int v[20];
    int s = 0;
    if (active) {
        const int4* dp = (const int4*)(deg + t * 20);
#pragma unroll
        for (int i = 0; i < 5; ++i) {
            int4 q = dp[i];
            v[i * 4 + 0] = q.x; v[i * 4 + 1] = q.y; v[i * 4 + 2] = q.z; v[i * 4 + 3] = q.w;
            s += q.x + q.y + q.z + q.w;
        }
    }
    part[t] = s;
    __syncthreads();
    for (int off = 1; off < 1024; off <<= 1) {
        int u = (t >= off) ? part[t - off] : 0;
        __syncthreads();
        part[t] += u;
        __syncthreads();
    }
    if (active) {
        int run = (t == 0) ? 0 : part[t - 1];
        int o[20];
#pragma unroll
        for (int i = 0; i < 20; ++i) { o[i] = run; run += v[i]; }
        int4* op = (int4*)(offsets + t * 20);
        int4* cp = (int4*)(cursor + t * 20);
#pragma unroll
        for (int i = 0; i < 5; ++i) {
            int4 q = {o[i * 4 + 0], o[i * 4 + 1], o[i * 4 + 2], o[i * 4 + 3]};
            op[i] = q;
            cp[i] = q;
        }
        if (t * 20 + 20 >= N) offsets[N] = run;   // t == 999
    }
}

__global__ __launch_bounds__(256) void fill_kernel(const int* __restrict__ ei,
                                                   int* __restrict__ cursor,
                                                   int* __restrict__ csr) {
    int e = blockIdx.x * 256 + threadIdx.x;
    if (e >= E) return;
    const int s = ei[e];          // src row
    const int d = ei[E + e];      // dst row
    const int pos = atomicAdd(&cursor[d], 1);
    csr[pos] = s;
}

// ---------------------------------------------------------------- gather/aggregate (bf16 h)
// 256 threads = 4 waves per block, one node per wave (node = blockIdx*4 + wave).
// lane l: batch b = l>>4, feature octet fq = l&15 (features 8fq..8fq+7), head = fq>>2.
// Per edge each lane loads one uint4 (16 B). x4 unrolled independent chains.
__global__ __launch_bounds__(256) void gather_kernel(const __hip_bfloat16* __restrict__ hb,
                                                     const float* __restrict__ asrc,
                                                     const float* __restrict__ adst,
                                                     const int* __restrict__ offsets,
                                                     const int* __restrict__ csr,
                                                     float* __restrict__ out) {
    const int t  = threadIdx.x;
    const int n  = blockIdx.x * 4 + (t >> 6);
    const int l  = t & 63;
    const int b  = l >> 4;
    const int fq = l & 15;
    const int hh = fq >> 2;

    const uint4* hu = (const uint4*)hb;           // idx = (s*B+b)*16 + fq = s*64 + bq
    const int bq   = b * 16 + fq;
    const int aoff = b * H + hh;                  // asrc idx = s*16 + aoff
    const float ad = adst[(size_t)n * 16 + aoff];
    const int j0 = offsets[n];
    const int j1 = offsets[n + 1];

    float ac[8];
#pragma unroll
    for (int i = 0; i < 8; ++i) ac[i] = 0.f;
    float den = 0.f;

    int j = j0;
    for (; j + 3 < j1; j += 4) {
        const int s0 = csr[j], s1 = csr[j + 1], s2 = csr[j + 2], s3 = csr[j + 3];
        const float l0 = asrc[(size_t)s0 * 16 + aoff];
        const float l1 = asrc[(size_t)s1 * 16 + aoff];
        const float l2 = asrc[(size_t)s2 * 16 + aoff];
        const float l3 = asrc[(size_t)s3 * 16 + aoff];
        const uint4 v0 = hu[(size_t)s0 * 64 + bq];
        const uint4 v1 = hu[(size_t)s1 * 64 + bq];
        const uint4 v2 = hu[(size_t)s2 * 64 + bq];
        const uint4 v3 = hu[(size_t)s3 * 64 + bq];
        float t0 = l0 + ad; t0 = (t0 >= 0.f) ? t0 : 0.2f * t0;
        float t1 = l1 + ad; t1 = (t1 >= 0.f) ? t1 : 0.2f * t1;
        float t2 = l2 + ad; t2 = (t2 >= 0.f) ? t2 : 0.2f * t2;
        float t3 = l3 + ad; t3 = (t3 >= 0.f) ? t3 : 0.2f * t3;
        const float e0 = __expf(t0), e1 = __expf(t1), e2 = __expf(t2), e3 = __expf(t3);
        den += e0 + e1 + e2 + e3;
        ac[0] += e0 * bflo(v0.x) + e1 * bflo(v1.x) + e2 * bflo(v2.x) + e3 * bflo(v3.x);
        ac[1] += e0 * bfhi(v0.x) + e1 * bfhi(v1.x) + e2 * bfhi(v2.x) + e3 * bfhi(v3.x);
        ac[2] += e0 * bflo(v0.y) + e1 * bflo(v1.y) + e2 * bflo(v2.y) + e3 * bflo(v3.y);
        ac[3] += e0 * bfhi(v0.y) + e1 * bfhi(v1.y) + e2 * bfhi(v2.y) + e3 * bfhi(v3.y);
        ac[4] += e0 * bflo(v0.z) + e1 * bflo(v1.z) + e2 * bflo(v2.z) + e3 * bflo(v3.z);
        ac[5] += e0 * bfhi(v0.z) + e1 * bfhi(v1.z) + e2 * bfhi(v2.z) + e3 * bfhi(v3.z);
        ac[6] += e0 * bflo(v0.w) + e1 * bflo(v1.w) + e2 * bflo(v2.w) + e3 * bflo(v3.w);
        ac[7] += e0 * bfhi(v0.w) + e1 * bfhi(v1.w) + e2 * bfhi(v2.w) + e3 * bfhi(v3.w);
    }
    for (; j < j1; ++j) {
        const int s0 = csr[j];
        const float l0 = asrc[(size_t)s0 * 16 + aoff];
        const uint4 v0 = hu[(size_t)s0 * 64 + bq];
        float t0 = l0 + ad; t0 = (t0 >= 0.f) ? t0 : 0.2f * t0;
        const float e0 = __expf(t0);
        den += e0;
        ac[0] += e0 * bflo(v0.x);
        ac[1] += e0 * bfhi(v0.x);
        ac[2] += e0 * bflo(v0.y);
        ac[3] += e0 * bfhi(v0.y);
        ac[4] += e0 * bflo(v0.z);
        ac[5] += e0 * bfhi(v0.z);
        ac[6] += e0 * bflo(v0.w);
        ac[7] += e0 * bfhi(v0.w);
    }
    const float inv = 1.0f / (den + 1e-10f);
    float4 o0 = {ac[0] * inv, ac[1] * inv, ac[2] * inv, ac[3] * inv};
    float4 o1 = {ac[4] * inv, ac[5] * inv, ac[6] * inv, ac[7] * inv};
    float4* op = (float4*)(out + ((size_t)b * N + n) * HF + fq * 8);
    op[0] = o0;
    op[1] = o1;
}

// ---------------------------------------------------------------- launch
extern "C" void kernel_launch(void* const* d_in, const int* in_sizes, int n_in,
                              void* d_out, int out_size, void* d_ws, size_t ws_size,
                              hipStream_t stream) {
    const float* x   = (const float*)d_in[0];
    const int*   ei  = (const int*)d_in[1];     // int32 (harness converts int64 -> int32)
    const float* W   = (const float*)d_in[2];
    const float* a   = (const float*)d_in[3];
    float*       out = (float*)d_out;

    // workspace carve (~25 MB total)
    char* p = (char*)d_ws;
    __hip_bfloat16* hb = (__hip_bfloat16*)p; p += (size_t)B * N * HF * sizeof(__hip_bfloat16); // 20,480,000 B
    float* asrc = (float*)p; p += (size_t)N * B * H * sizeof(float);    // 1,280,000 B
    float* adst = (float*)p; p += (size_t)N * B * H * sizeof(float);    // 1,280,000 B
    int* deg     = (int*)p;  p += 80128;
    int* offsets = (int*)p;  p += 80128;
    int* cursor  = (int*)p;  p += 80128;
    int* csr     = (int*)p;  p += (size_t)E * sizeof(int);              // 1,280,000 B
    __hip_bfloat16* wt = (__hip_bfloat16*)p; p += (size_t)HF * INF * sizeof(__hip_bfloat16); // 32,768 B

    init_kernel<<<(N + 255) / 256, 256, 0, stream>>>(W, wt, deg);
    gemm_mfma_kernel<<<(B * N) / 64, 256, 0, stream>>>(x, wt, a, hb, asrc, adst);
    hist_kernel<<<(E + 255) / 256, 256, 0, stream>>>(ei + E, deg);
    scan_kernel<<<1, 1024, 0, stream>>>(deg, offsets, cursor);
    fill_kernel<<<(E + 255) / 256, 256, 0, stream>>>(ei, cursor, csr);
    gather_kernel<<<(N / 4), 256, 0, stream>>>(hb, asrc, adst, offsets, csr, out);
}